// Round 5
// baseline (2287.231 us; speedup 1.0000x reference)
//
#include <hip/hip_runtime.h>
#include <hip/hip_bf16.h>

// ModalityEnhancedLSTM: B=64, S=1024, D=256, H=256.
// out = [hidden_seq (64*1024*256) | h_t (64*256) | c_t (64*256)] f32.
//
//  prep_kernel : W -> bf16 B-frag layout; U -> NEGATED bf16 B-frag layout
//                (MFMA((-h),(-U)) == h@U; writers store -h => nonzero bf16
//                pattern => data-is-the-flag poll, no separate flags).
//  xproj_kernel: xp = x@W + bias, bf16, [wg][t][slice][lane][4] layout.
//  lstm_kernel : grid 32 = 4 groups(16 b) x 8 colWGs(32 j). U slice in regs.
//                EARLY per-wave publish: each active lane stores its 4 bf16
//                (-h) values (2B stores, sc0 sc1 -> L3) right after computing
//                h, before any barrier. Readers: single combined poll of all
//                8 blocks (8x16B sc0 sc1 loads + v_pk_min_u16 all-nonzero
//                check). Wave 8 = service wave (xp global_load_lds ring with
//                counted vmcnt, hidden_seq f32 stores). Raw s_barrier with
//                lgkmcnt-only drain (no per-step vmcnt(0) drain).
//
//  NOTE (round-4 post-mortem): no XCD/sc0-only fast path. A store whose scope
//  is below the common coherence point can never be observed by a cross-XCD
//  reader -> unbounded poll -> hang. All exchange is sc0 sc1 (L3), proven.

#define BSH 16777216u   // 64*1024*256
#define BH  16384u

typedef short short8 __attribute__((ext_vector_type(8)));
typedef float float4_ __attribute__((ext_vector_type(4)));
typedef unsigned int uint2_ __attribute__((ext_vector_type(2)));
typedef unsigned int uint4_ __attribute__((ext_vector_type(4)));

static __device__ __forceinline__ unsigned short f2bf(float f) {
    unsigned int u = __builtin_bit_cast(unsigned int, f);
    u += 0x7FFFu + ((u >> 16) & 1u);
    return (unsigned short)(u >> 16);
}
static __device__ __forceinline__ float bf2f(unsigned short h) {
    unsigned int u = ((unsigned int)h) << 16;
    return __builtin_bit_cast(float, u);
}
static __device__ __forceinline__ uint4_ pack8(const unsigned short* t) {
    uint4_ v;
    v.x = (unsigned int)t[0] | ((unsigned int)t[1] << 16);
    v.y = (unsigned int)t[2] | ((unsigned int)t[3] << 16);
    v.z = (unsigned int)t[4] | ((unsigned int)t[5] << 16);
    v.w = (unsigned int)t[6] | ((unsigned int)t[7] << 16);
    return v;
}
static __device__ __forceinline__ unsigned pkmin16(unsigned a, unsigned b) {
    unsigned d;
    asm("v_pk_min_u16 %0, %1, %2" : "=v"(d) : "v"(a), "v"(b));
    return d;
}
static __device__ __forceinline__ void gload_lds16(const void* g, void* l) {
    __builtin_amdgcn_global_load_lds(
        (const __attribute__((address_space(1))) unsigned int*)g,
        (__attribute__((address_space(3))) unsigned int*)l, 16, 0, 0);
}
static __device__ __forceinline__ void barrier_lgkm() {
    asm volatile("s_waitcnt lgkmcnt(0)" ::: "memory");
    __builtin_amdgcn_s_barrier();
    asm volatile("" ::: "memory");
}

// ---------------- prep: W,(-U) -> bf16 frag layout; bias -> per-slice -------
__global__ void prep_kernel(const float* __restrict__ W, const float* __restrict__ U,
                            const float* __restrict__ bias,
                            unsigned short* __restrict__ Wbf, unsigned short* __restrict__ Ubf,
                            float* __restrict__ biasf) {
    int tid = blockIdx.x * blockDim.x + threadIdx.x;
    if (tid < 65536) {
        int idx = tid & 32767;
        const bool isU = (tid >= 32768);
        const float* src = isU ? U : W;
        unsigned short* dst = isU ? Ubf : Wbf;
        int sl = idx >> 9, kt = (idx >> 6) & 7, lane = idx & 63;
        int c = lane & 15, kgrp = lane >> 4;
        int m = sl >> 3, wv = sl & 7;
        int gatec = c >> 2, jj = c & 3;
        int ncol = gatec * 256 + 32 * m + 4 * wv + jj;
        unsigned short t8[8];
#pragma unroll
        for (int e = 0; e < 8; e++) {
            int k = kt * 32 + kgrp * 8 + e;
            float v = src[k * 1024 + ncol];
            t8[e] = f2bf(isU ? -v : v);
        }
        *(uint4_*)(dst + (size_t)idx * 8) = pack8(t8);
    } else if (tid < 66560) {
        int idx2 = tid - 65536;            // [0,1024)
        int sl = idx2 >> 4, c = idx2 & 15;
        int m = sl >> 3, wv = sl & 7, gatec = c >> 2, jj = c & 3;
        int ncol = gatec * 256 + 32 * m + 4 * wv + jj;
        biasf[idx2] = bias[ncol];
    }
}

// ---------------- xproj: xp = x @ W + bias, bf16, per-WG layout -------------
__global__ __launch_bounds__(512, 2)
void xproj_kernel(const float* __restrict__ x, const unsigned short* __restrict__ Wbf,
                  const float* __restrict__ biasf, unsigned short* __restrict__ xp) {
    const int bx = blockIdx.x;             // [0,1024)
    const int g = bx & 3, tile = bx >> 2;  // 256 tiles of 4 s each
    const int s0 = tile * 4;
    const int tidx = threadIdx.x;
    const int w = tidx >> 6, lane = tidx & 63;

    __shared__ unsigned short Afrag[4][8][64][8];  // [si][kt][lane][e] 32KB

    {   // stage x (f32 -> bf16 A-frags)
        int row = tidx >> 3;               // 0..63 = si*16 + r
        int kt = tidx & 7;
        int si = row >> 4, r = row & 15;
        int b = g * 16 + r, s = s0 + si;
        const float* px = x + ((size_t)b * 1024 + s) * 256 + kt * 32;
#pragma unroll
        for (int kg = 0; kg < 4; kg++) {
            float4_ v0 = *(const float4_*)(px + kg * 8);
            float4_ v1 = *(const float4_*)(px + kg * 8 + 4);
            unsigned short t8[8] = { f2bf(v0.x), f2bf(v0.y), f2bf(v0.z), f2bf(v0.w),
                                     f2bf(v1.x), f2bf(v1.y), f2bf(v1.z), f2bf(v1.w) };
            *(uint4_*)&Afrag[si][kt][kg * 16 + r][0] = pack8(t8);
        }
    }
    __syncthreads();

    float4_ acc[8][4];
#pragma unroll
    for (int q = 0; q < 8; q++) {
        int sl = w * 8 + q;
        float bv = biasf[sl * 16 + (lane & 15)];
#pragma unroll
        for (int si = 0; si < 4; si++) acc[q][si] = (float4_){bv, bv, bv, bv};
    }
#pragma unroll
    for (int kt = 0; kt < 8; kt++) {
        short8 a[4];
#pragma unroll
        for (int si = 0; si < 4; si++)
            a[si] = *(const short8*)&Afrag[si][kt][lane][0];
#pragma unroll
        for (int q = 0; q < 8; q++) {
            short8 bfr = *(const short8*)(Wbf + (((size_t)(w * 8 + q) * 8 + kt) * 64 + lane) * 8);
#pragma unroll
            for (int si = 0; si < 4; si++)
                acc[q][si] = __builtin_amdgcn_mfma_f32_16x16x32_bf16(a[si], bfr, acc[q][si], 0, 0, 0);
        }
    }
#pragma unroll
    for (int q = 0; q < 8; q++) {
        int sl = w * 8 + q;
        int wgx = g * 8 + (sl >> 3);
#pragma unroll
        for (int si = 0; si < 4; si++) {
            int s = s0 + si;
            unsigned int lo = (unsigned int)f2bf(acc[q][si].x) | ((unsigned int)f2bf(acc[q][si].y) << 16);
            unsigned int hi = (unsigned int)f2bf(acc[q][si].z) | ((unsigned int)f2bf(acc[q][si].w) << 16);
            uint2_ v = {lo, hi};
            *(uint2_*)(xp + ((((size_t)wgx * 1024 + s) * 8 + (sl & 7)) * 64 + lane) * 4) = v;
        }
    }
}

// ---------------- recurrent scan -------------------------------------------
__global__ __launch_bounds__(576, 1)
void lstm_kernel(const unsigned short* __restrict__ Ubf,
                 const unsigned short* __restrict__ xp,
                 const float* __restrict__ lam,
                 unsigned short* __restrict__ hbuf,   // zero-initialized
                 float* __restrict__ out) {
    const int bx = blockIdx.x;             // grid 32
    const int g = bx & 3;                  // batch group 0..3
    const int m = bx >> 2;                 // colWG 0..7
    const int tid = threadIdx.x;
    const int w = tid >> 6, lane = tid & 63;

    __shared__ float lamLDS[1024];
    __shared__ unsigned short htmp[2][16][40];   // -h, bf16, padded rows
    __shared__ unsigned short xpring[8][2048];   // [slot][slice*256 + lane*4]

    for (int i = tid; i < 1024; i += 576) lamLDS[i] = lam[i];

    const int col = lane & 15;
    const int gatec = col >> 2, jj = col & 3;
    const int rr0 = (lane >> 4) * 4;
    const bool active = (gatec == 0);

    short8 u[8];
    if (w < 8) {
        int sl = m * 8 + w;
#pragma unroll
        for (int kt = 0; kt < 8; kt++)
            u[kt] = *(const short8*)(Ubf + (((size_t)sl * 8 + kt) * 64 + lane) * 8);
    }

    const size_t wgx = (size_t)(g * 8 + m);

    if (w == 8) {   // prologue: prefetch xp steps 0..5
        for (int s = 0; s < 6; s++) {
            const char* src = (const char*)xp + ((wgx * 1024 + s) << 12) + (size_t)lane * 16;
            char* dst = (char*)&xpring[s][0];
#pragma unroll
            for (int c2 = 0; c2 < 4; c2++)
                gload_lds16(src + c2 * 1024, dst + c2 * 1024);
        }
        asm volatile("s_waitcnt vmcnt(20)" ::: "memory");   // slot 0 ready
    }

    float cst[4] = {0.f, 0.f, 0.f, 0.f};
    barrier_lgkm();

    // publish pointer (t=0): -h element (row rr0, col u_col) of block m
    const int u_col = 4 * w + jj;
    char* hpub = (char*)hbuf + ((size_t)g << 13) + (size_t)m * 1024
               + (size_t)((u_col >> 3) * 256 + rr0 * 16 + (u_col & 7) * 2);
    // poll pointers: represent step t-1, advanced at end of each iteration
    const char* pbl = (const char*)hbuf + ((size_t)g << 13) + (size_t)lane * 16 - 32768;
    const char* pbh = pbl + 4096;

    for (int t = 0; t < 1024; t++) {
        if (w < 8) {
            unsigned long long xpd =
                *(const unsigned long long*)&xpring[t & 7][w * 256 + lane * 4];
            float4_ acc0, acc1 = (float4_){0.f, 0.f, 0.f, 0.f};
            acc0.x = bf2f((unsigned short)(xpd & 0xffff));
            acc0.y = bf2f((unsigned short)((xpd >> 16) & 0xffff));
            acc0.z = bf2f((unsigned short)((xpd >> 32) & 0xffff));
            acc0.w = bf2f((unsigned short)(xpd >> 48));

            if (t > 0) {
                uint4_ r0, r1, r2, r3, r4, r5, r6, r7;
                for (;;) {   // combined poll+fetch: every bf16 half nonzero
                    asm volatile(
                        "global_load_dwordx4 %0, %8, off sc0 sc1\n\t"
                        "global_load_dwordx4 %1, %8, off offset:1024 sc0 sc1\n\t"
                        "global_load_dwordx4 %2, %8, off offset:2048 sc0 sc1\n\t"
                        "global_load_dwordx4 %3, %8, off offset:3072 sc0 sc1\n\t"
                        "global_load_dwordx4 %4, %9, off sc0 sc1\n\t"
                        "global_load_dwordx4 %5, %9, off offset:1024 sc0 sc1\n\t"
                        "global_load_dwordx4 %6, %9, off offset:2048 sc0 sc1\n\t"
                        "global_load_dwordx4 %7, %9, off offset:3072 sc0 sc1\n\t"
                        "s_waitcnt vmcnt(0)"
                        : "=v"(r0), "=v"(r1), "=v"(r2), "=v"(r3),
                          "=v"(r4), "=v"(r5), "=v"(r6), "=v"(r7)
                        : "v"(pbl), "v"(pbh) : "memory");
                    __builtin_amdgcn_sched_barrier(0);
                    unsigned q0 = pkmin16(pkmin16(r0.x, r0.y), pkmin16(r0.z, r0.w));
                    unsigned q1 = pkmin16(pkmin16(r1.x, r1.y), pkmin16(r1.z, r1.w));
                    unsigned q2 = pkmin16(pkmin16(r2.x, r2.y), pkmin16(r2.z, r2.w));
                    unsigned q3 = pkmin16(pkmin16(r3.x, r3.y), pkmin16(r3.z, r3.w));
                    unsigned q4 = pkmin16(pkmin16(r4.x, r4.y), pkmin16(r4.z, r4.w));
                    unsigned q5 = pkmin16(pkmin16(r5.x, r5.y), pkmin16(r5.z, r5.w));
                    unsigned q6 = pkmin16(pkmin16(r6.x, r6.y), pkmin16(r6.z, r6.w));
                    unsigned q7 = pkmin16(pkmin16(r7.x, r7.y), pkmin16(r7.z, r7.w));
                    unsigned mm = pkmin16(pkmin16(pkmin16(q0, q1), pkmin16(q2, q3)),
                                          pkmin16(pkmin16(q4, q5), pkmin16(q6, q7)));
                    if (__all(((mm & 0xffffu) != 0u) && ((mm >> 16) != 0u))) break;
                }
                acc0 = __builtin_amdgcn_mfma_f32_16x16x32_bf16(__builtin_bit_cast(short8, r0), u[0], acc0, 0, 0, 0);
                acc1 = __builtin_amdgcn_mfma_f32_16x16x32_bf16(__builtin_bit_cast(short8, r1), u[1], acc1, 0, 0, 0);
                acc0 = __builtin_amdgcn_mfma_f32_16x16x32_bf16(__builtin_bit_cast(short8, r2), u[2], acc0, 0, 0, 0);
                acc1 = __builtin_amdgcn_mfma_f32_16x16x32_bf16(__builtin_bit_cast(short8, r3), u[3], acc1, 0, 0, 0);
                acc0 = __builtin_amdgcn_mfma_f32_16x16x32_bf16(__builtin_bit_cast(short8, r4), u[4], acc0, 0, 0, 0);
                acc1 = __builtin_amdgcn_mfma_f32_16x16x32_bf16(__builtin_bit_cast(short8, r5), u[5], acc1, 0, 0, 0);
                acc0 = __builtin_amdgcn_mfma_f32_16x16x32_bf16(__builtin_bit_cast(short8, r6), u[6], acc0, 0, 0, 0);
                acc1 = __builtin_amdgcn_mfma_f32_16x16x32_bf16(__builtin_bit_cast(short8, r7), u[7], acc1, 0, 0, 0);
            }

            float lamt = lamLDS[t];
            float gv[4], fv[4], ggv[4], ov[4];
#pragma unroll
            for (int q = 0; q < 4; q++) {
                float xg = acc0[q] + acc1[q];
                float y = (gatec == 2) ? 2.f * xg : xg;
                float sgm = 1.f / (1.f + __expf(-y));
                gv[q] = (gatec == 2) ? 2.f * sgm - 1.f : sgm;
            }
#pragma unroll
            for (int q = 0; q < 4; q++) {
                fv[q]  = __shfl(gv[q], lane + 4, 64);
                ggv[q] = __shfl(gv[q], lane + 8, 64);
                ov[q]  = __shfl(gv[q], lane + 12, 64);
            }
            if (active) {
                float hq[4];
                unsigned short hb[4];
#pragma unroll
                for (int q = 0; q < 4; q++) {
                    float c = fv[q] * cst[q] + gv[q] * ggv[q] * lamt;
                    cst[q] = c;
                    float th = 2.f / (1.f + __expf(-2.f * c)) - 1.f;
                    hq[q] = ov[q] * th;
                    unsigned short b = f2bf(-hq[q]);
                    if (b == 0) b = 0x8000u;   // -0.0: numerically 0, bits != 0
                    hb[q] = b;
                }
                // EARLY publish: fire-and-forget, data-is-the-flag (L3)
                asm volatile("global_store_short %0, %1, off sc0 sc1"            :: "v"(hpub), "v"((unsigned)hb[0]) : "memory");
                asm volatile("global_store_short %0, %1, off offset:16 sc0 sc1"  :: "v"(hpub), "v"((unsigned)hb[1]) : "memory");
                asm volatile("global_store_short %0, %1, off offset:32 sc0 sc1"  :: "v"(hpub), "v"((unsigned)hb[2]) : "memory");
                asm volatile("global_store_short %0, %1, off offset:48 sc0 sc1"  :: "v"(hpub), "v"((unsigned)hb[3]) : "memory");
#pragma unroll
                for (int q = 0; q < 4; q++)
                    htmp[t & 1][rr0 + q][4 * w + jj] = hb[q];
                if (t == 1023) {
#pragma unroll
                    for (int q = 0; q < 4; q++) {
                        size_t b = (size_t)g * 16 + rr0 + q;
                        int j = m * 32 + 4 * w + jj;
                        out[BSH + b * 256 + j] = hq[q];
                        out[BSH + BH + b * 256 + j] = cst[q];
                    }
                }
            }
        } else if (w == 8) {
            // 1) issue xp prefetch for step t+6
            if (t + 6 < 1024) {
                int slot = (t + 6) & 7;
                const char* src = (const char*)xp + ((wgx * 1024 + (size_t)(t + 6)) << 12)
                                  + (size_t)lane * 16;
                char* dst = (char*)&xpring[slot][0];
#pragma unroll
                for (int c2 = 0; c2 < 4; c2++)
                    gload_lds16(src + c2 * 1024, dst + c2 * 1024);
            }
            // 2) hidden_seq stores for step t-1
            if (t > 0) {
                int r = lane >> 2, seg = lane & 3;
                uint4_ hv = *(const uint4_*)&htmp[(t - 1) & 1][r][seg * 8];
                hv.x ^= 0x80008000u; hv.y ^= 0x80008000u;
                hv.z ^= 0x80008000u; hv.w ^= 0x80008000u;   // -(-h) = h
                float4_ v0 = { bf2f((unsigned short)(hv.x & 0xffff)), bf2f((unsigned short)(hv.x >> 16)),
                               bf2f((unsigned short)(hv.y & 0xffff)), bf2f((unsigned short)(hv.y >> 16)) };
                float4_ v1 = { bf2f((unsigned short)(hv.z & 0xffff)), bf2f((unsigned short)(hv.z >> 16)),
                               bf2f((unsigned short)(hv.w & 0xffff)), bf2f((unsigned short)(hv.w >> 16)) };
                float* po = out + (((size_t)(g * 16 + r)) << 18) + ((size_t)(t - 1) << 8)
                            + m * 32 + seg * 8;
                *(float4_*)po = v0;
                *(float4_*)(po + 4) = v1;
            }
            // 3) guarantee slot t+1 is resident before the barrier (counted!)
            if (t == 0)            asm volatile("s_waitcnt vmcnt(20)" ::: "memory");
            else if (t == 1)       asm volatile("s_waitcnt vmcnt(22)" ::: "memory");
            else if (t + 6 < 1024) asm volatile("s_waitcnt vmcnt(24)" ::: "memory");
            else                   asm volatile("s_waitcnt vmcnt(0)"  ::: "memory");
        }
        barrier_lgkm();
        hpub += 32768;
        pbl += 32768;
        pbh += 32768;
    }
    // epilogue: hidden_seq for t=1023
    if (w == 8) {
        int r = lane >> 2, seg = lane & 3;
        uint4_ hv = *(const uint4_*)&htmp[1][r][seg * 8];
        hv.x ^= 0x80008000u; hv.y ^= 0x80008000u;
        hv.z ^= 0x80008000u; hv.w ^= 0x80008000u;
        float4_ v0 = { bf2f((unsigned short)(hv.x & 0xffff)), bf2f((unsigned short)(hv.x >> 16)),
                       bf2f((unsigned short)(hv.y & 0xffff)), bf2f((unsigned short)(hv.y >> 16)) };
        float4_ v1 = { bf2f((unsigned short)(hv.z & 0xffff)), bf2f((unsigned short)(hv.z >> 16)),
                       bf2f((unsigned short)(hv.w & 0xffff)), bf2f((unsigned short)(hv.w >> 16)) };
        float* po = out + (((size_t)(g * 16 + r)) << 18) + ((size_t)1023 << 8) + m * 32 + seg * 8;
        *(float4_*)po = v0;
        *(float4_*)(po + 4) = v1;
    }
}

__global__ void ws_too_small_kernel(float* out) {
    if (threadIdx.x == 0 && blockIdx.x == 0) out[0] = -777777.0f;
}

extern "C" void kernel_launch(void* const* d_in, const int* in_sizes, int n_in,
                              void* d_out, int out_size, void* d_ws, size_t ws_size,
                              hipStream_t stream) {
    const float* x    = (const float*)d_in[0];
    const float* lam  = (const float*)d_in[1];
    const float* W    = (const float*)d_in[2];
    const float* U    = (const float*)d_in[3];
    const float* bias = (const float*)d_in[4];
    float* out = (float*)d_out;

    const size_t NEED = (size_t)162 << 20;   // 2MiB prep + 32MiB hbuf + 128MiB xp
    if (ws_size < NEED) {
        ws_too_small_kernel<<<1, 64, 0, stream>>>(out);
        return;
    }
    char* ws = (char*)d_ws;
    unsigned short* Ubf   = (unsigned short*)(ws + (256 << 10));       // 512KB
    unsigned short* Wbf   = (unsigned short*)(ws + (768 << 10));       // 512KB
    float*          biasf = (float*)(ws + (1280 << 10));               // 4KB
    unsigned short* hbuf  = (unsigned short*)(ws + ((size_t)2 << 20)); // 32MiB
    unsigned short* xp    = (unsigned short*)(ws + ((size_t)34 << 20));// 128MiB

    hipMemsetAsync(hbuf, 0, (size_t)32 << 20, stream);   // sentinel for data-poll
    prep_kernel<<<260, 256, 0, stream>>>(W, U, bias, Wbf, Ubf, biasf);
    xproj_kernel<<<1024, 512, 0, stream>>>(x, Wbf, biasf, xp);
    lstm_kernel<<<32, 576, 0, stream>>>(Ubf, xp, lam, hbuf, out);
}

// Round 7
// 2223.538 us; speedup vs baseline: 1.0286x; 1.0286x over previous
//
#include <hip/hip_runtime.h>
#include <hip/hip_bf16.h>

// ModalityEnhancedLSTM: B=64, S=1024, D=256, H=256.
// out = [hidden_seq (64*1024*256) | h_t (64*256) | c_t (64*256)] f32.
//
//  prep_kernel : W -> bf16 B-frag layout; U -> NEGATED bf16 B-frag layout
//                (MFMA((-h),(-U)) == h@U; writers store -h => nonzero bf16
//                pattern => data-is-the-flag poll, no separate flags).
//  xproj_kernel: xp = x@W + bias, bf16, [wg][t][slice][lane][4] layout.
//  lstm_kernel : grid 32 = 4 groups(16 b) x 8 colWGs(32 j). U slice in regs.
//                Exchange: per-wave DEDUP poll (wave w polls ONLY block kt=w,
//                1KB) -> ds_write to double-buffered hstage -> one lgkm-only
//                s_barrier -> all waves ds_read all 8 blocks. Publish: htmp
//                LDS transpose -> 8B global_store_dwordx2 sc0 sc1 (full-dword
//                granularity; no partial-line HBM amplification). Per-dword
//                nonzero check is sound: each dword comes entirely from one
//                aligned 8B store; -0.0 guard keeps every stored bf16
//                nonzero. Service wave: xp global_load_lds ring with counted
//                vmcnt; hidden_seq stores post-barrier.
//
//  ROUND-6 BUG FIX: the barrier moved to mid-loop, so iteration 1023's htmp
//  writes had NO barrier before wave 8's epilogue read of htmp[1] -> stale
//  t=1023 hidden_seq row (absmax 0.638). Fix: trailing barrier_lgkm() after
//  the loop (unconditional, all 9 waves, balanced).

#define BSH 16777216u   // 64*1024*256
#define BH  16384u

typedef short short8 __attribute__((ext_vector_type(8)));
typedef float float4_ __attribute__((ext_vector_type(4)));
typedef unsigned int uint2_ __attribute__((ext_vector_type(2)));
typedef unsigned int uint4_ __attribute__((ext_vector_type(4)));

static __device__ __forceinline__ unsigned short f2bf(float f) {
    unsigned int u = __builtin_bit_cast(unsigned int, f);
    u += 0x7FFFu + ((u >> 16) & 1u);
    return (unsigned short)(u >> 16);
}
static __device__ __forceinline__ float bf2f(unsigned short h) {
    unsigned int u = ((unsigned int)h) << 16;
    return __builtin_bit_cast(float, u);
}
static __device__ __forceinline__ uint4_ pack8(const unsigned short* t) {
    uint4_ v;
    v.x = (unsigned int)t[0] | ((unsigned int)t[1] << 16);
    v.y = (unsigned int)t[2] | ((unsigned int)t[3] << 16);
    v.z = (unsigned int)t[4] | ((unsigned int)t[5] << 16);
    v.w = (unsigned int)t[6] | ((unsigned int)t[7] << 16);
    return v;
}
static __device__ __forceinline__ unsigned umin_(unsigned a, unsigned b) {
    return a < b ? a : b;
}
static __device__ __forceinline__ void gload_lds16(const void* g, void* l) {
    __builtin_amdgcn_global_load_lds(
        (const __attribute__((address_space(1))) unsigned int*)g,
        (__attribute__((address_space(3))) unsigned int*)l, 16, 0, 0);
}
static __device__ __forceinline__ void barrier_lgkm() {
    asm volatile("s_waitcnt lgkmcnt(0)" ::: "memory");
    __builtin_amdgcn_s_barrier();
    asm volatile("" ::: "memory");
}

// ---------------- prep: W,(-U) -> bf16 frag layout; bias -> per-slice -------
__global__ void prep_kernel(const float* __restrict__ W, const float* __restrict__ U,
                            const float* __restrict__ bias,
                            unsigned short* __restrict__ Wbf, unsigned short* __restrict__ Ubf,
                            float* __restrict__ biasf) {
    int tid = blockIdx.x * blockDim.x + threadIdx.x;
    if (tid < 65536) {
        int idx = tid & 32767;
        const bool isU = (tid >= 32768);
        const float* src = isU ? U : W;
        unsigned short* dst = isU ? Ubf : Wbf;
        int sl = idx >> 9, kt = (idx >> 6) & 7, lane = idx & 63;
        int c = lane & 15, kgrp = lane >> 4;
        int m = sl >> 3, wv = sl & 7;
        int gatec = c >> 2, jj = c & 3;
        int ncol = gatec * 256 + 32 * m + 4 * wv + jj;
        unsigned short t8[8];
#pragma unroll
        for (int e = 0; e < 8; e++) {
            int k = kt * 32 + kgrp * 8 + e;
            float v = src[k * 1024 + ncol];
            t8[e] = f2bf(isU ? -v : v);
        }
        *(uint4_*)(dst + (size_t)idx * 8) = pack8(t8);
    } else if (tid < 66560) {
        int idx2 = tid - 65536;            // [0,1024)
        int sl = idx2 >> 4, c = idx2 & 15;
        int m = sl >> 3, wv = sl & 7, gatec = c >> 2, jj = c & 3;
        int ncol = gatec * 256 + 32 * m + 4 * wv + jj;
        biasf[idx2] = bias[ncol];
    }
}

// ---------------- xproj: xp = x @ W + bias, bf16, per-WG layout -------------
__global__ __launch_bounds__(512, 2)
void xproj_kernel(const float* __restrict__ x, const unsigned short* __restrict__ Wbf,
                  const float* __restrict__ biasf, unsigned short* __restrict__ xp) {
    const int bx = blockIdx.x;             // [0,1024)
    const int g = bx & 3, tile = bx >> 2;  // 256 tiles of 4 s each
    const int s0 = tile * 4;
    const int tidx = threadIdx.x;
    const int w = tidx >> 6, lane = tidx & 63;

    __shared__ unsigned short Afrag[4][8][64][8];  // [si][kt][lane][e] 32KB

    {   // stage x (f32 -> bf16 A-frags)
        int row = tidx >> 3;               // 0..63 = si*16 + r
        int kt = tidx & 7;
        int si = row >> 4, r = row & 15;
        int b = g * 16 + r, s = s0 + si;
        const float* px = x + ((size_t)b * 1024 + s) * 256 + kt * 32;
#pragma unroll
        for (int kg = 0; kg < 4; kg++) {
            float4_ v0 = *(const float4_*)(px + kg * 8);
            float4_ v1 = *(const float4_*)(px + kg * 8 + 4);
            unsigned short t8[8] = { f2bf(v0.x), f2bf(v0.y), f2bf(v0.z), f2bf(v0.w),
                                     f2bf(v1.x), f2bf(v1.y), f2bf(v1.z), f2bf(v1.w) };
            *(uint4_*)&Afrag[si][kt][kg * 16 + r][0] = pack8(t8);
        }
    }
    __syncthreads();

    float4_ acc[8][4];
#pragma unroll
    for (int q = 0; q < 8; q++) {
        int sl = w * 8 + q;
        float bv = biasf[sl * 16 + (lane & 15)];
#pragma unroll
        for (int si = 0; si < 4; si++) acc[q][si] = (float4_){bv, bv, bv, bv};
    }
#pragma unroll
    for (int kt = 0; kt < 8; kt++) {
        short8 a[4];
#pragma unroll
        for (int si = 0; si < 4; si++)
            a[si] = *(const short8*)&Afrag[si][kt][lane][0];
#pragma unroll
        for (int q = 0; q < 8; q++) {
            short8 bfr = *(const short8*)(Wbf + (((size_t)(w * 8 + q) * 8 + kt) * 64 + lane) * 8);
#pragma unroll
            for (int si = 0; si < 4; si++)
                acc[q][si] = __builtin_amdgcn_mfma_f32_16x16x32_bf16(a[si], bfr, acc[q][si], 0, 0, 0);
        }
    }
#pragma unroll
    for (int q = 0; q < 8; q++) {
        int sl = w * 8 + q;
        int wgx = g * 8 + (sl >> 3);
#pragma unroll
        for (int si = 0; si < 4; si++) {
            int s = s0 + si;
            unsigned int lo = (unsigned int)f2bf(acc[q][si].x) | ((unsigned int)f2bf(acc[q][si].y) << 16);
            unsigned int hi = (unsigned int)f2bf(acc[q][si].z) | ((unsigned int)f2bf(acc[q][si].w) << 16);
            uint2_ v = {lo, hi};
            *(uint2_*)(xp + ((((size_t)wgx * 1024 + s) * 8 + (sl & 7)) * 64 + lane) * 4) = v;
        }
    }
}

// ---------------- recurrent scan -------------------------------------------
__global__ __launch_bounds__(576, 1)
void lstm_kernel(const unsigned short* __restrict__ Ubf,
                 const unsigned short* __restrict__ xp,
                 const float* __restrict__ lam,
                 unsigned short* __restrict__ hbuf,   // zero-initialized
                 float* __restrict__ out) {
    const int bx = blockIdx.x;             // grid 32
    const int g = bx & 3;                  // batch group 0..3
    const int m = bx >> 2;                 // colWG 0..7
    const int tid = threadIdx.x;
    const int w = tid >> 6, lane = tid & 63;

    __shared__ float lamLDS[1024];
    __shared__ alignas(16) unsigned short htmp[2][16][40];     // -h bf16
    __shared__ alignas(16) unsigned short xpring[8][2048];     // xp ring
    __shared__ alignas(16) unsigned short hstage[2][8][64][8]; // polled h blocks

    for (int i = tid; i < 1024; i += 576) lamLDS[i] = lam[i];

    const int col = lane & 15;
    const int gatec = col >> 2, jj = col & 3;
    const int rr0 = (lane >> 4) * 4;
    const bool active = (gatec == 0);

    short8 u[8];
    if (w < 8) {
        int sl = m * 8 + w;
#pragma unroll
        for (int kt = 0; kt < 8; kt++)
            u[kt] = *(const short8*)(Ubf + (((size_t)sl * 8 + kt) * 64 + lane) * 8);
    }

    const size_t wgx = (size_t)(g * 8 + m);

    if (w == 8) {   // prologue: prefetch xp steps 0..5
        for (int s = 0; s < 6; s++) {
            const char* src = (const char*)xp + ((wgx * 1024 + s) << 12) + (size_t)lane * 16;
            char* dst = (char*)&xpring[s][0];
#pragma unroll
            for (int c2 = 0; c2 < 4; c2++)
                gload_lds16(src + c2 * 1024, dst + c2 * 1024);
        }
        asm volatile("s_waitcnt vmcnt(20)" ::: "memory");   // slot 0 ready
    }

    float cst[4] = {0.f, 0.f, 0.f, 0.f};
    barrier_lgkm();

    // publish pointer: WG m's wave w writes rows (lane<16) of cols 4w..4w+3
    // into block m: byte = (w>>1)*256 + lane*16 + (w&1)*8  (8B chunks).
    char* hpub = (char*)hbuf + ((size_t)g << 13) + (size_t)m * 1024
               + (size_t)((w >> 1) * 256 + (w & 1) * 8) + (size_t)lane * 16;
    // dedup poll pointer: wave w polls ONLY block kt=w of step t-1
    const char* pb = (const char*)hbuf + ((size_t)g << 13) + (size_t)w * 1024
                   + (size_t)lane * 16 - 32768;

    for (int t = 0; t < 1024; t++) {
        // ---------- pre-barrier: minimal critical path ----------
        if (w < 8) {
            if (t > 0) {
                uint4_ r;
                for (;;) {   // poll own 1KB block until all dwords nonzero
                    asm volatile("global_load_dwordx4 %0, %1, off sc0 sc1\n\t"
                                 "s_waitcnt vmcnt(0)"
                                 : "=v"(r) : "v"(pb) : "memory");
                    __builtin_amdgcn_sched_barrier(0);
                    if (__all(umin_(umin_(r.x, r.y), umin_(r.z, r.w)) != 0u)) break;
                }
                *(uint4_*)&hstage[t & 1][w][lane][0] = r;   // ds_write_b128
            }
        } else if (w == 8) {
            if (t + 6 < 1024) {
                int slot = (t + 6) & 7;
                const char* src = (const char*)xp + ((wgx * 1024 + (size_t)(t + 6)) << 12)
                                  + (size_t)lane * 16;
                char* dst = (char*)&xpring[slot][0];
#pragma unroll
                for (int c2 = 0; c2 < 4; c2++)
                    gload_lds16(src + c2 * 1024, dst + c2 * 1024);
            }
            // guarantee xp slot t+1 resident before the barrier (counted)
            if (t == 0)            asm volatile("s_waitcnt vmcnt(20)" ::: "memory");
            else if (t == 1)       asm volatile("s_waitcnt vmcnt(22)" ::: "memory");
            else if (t + 6 < 1024) asm volatile("s_waitcnt vmcnt(24)" ::: "memory");
            else                   asm volatile("s_waitcnt vmcnt(0)"  ::: "memory");
        }
        barrier_lgkm();
        // ---------- post-barrier ----------
        if (w < 8) {
            unsigned long long xpd =
                *(const unsigned long long*)&xpring[t & 7][w * 256 + lane * 4];
            float4_ acc0, acc1 = (float4_){0.f, 0.f, 0.f, 0.f};
            acc0.x = bf2f((unsigned short)(xpd & 0xffff));
            acc0.y = bf2f((unsigned short)((xpd >> 16) & 0xffff));
            acc0.z = bf2f((unsigned short)((xpd >> 32) & 0xffff));
            acc0.w = bf2f((unsigned short)(xpd >> 48));

            if (t > 0) {
                short8 a0 = *(const short8*)&hstage[t & 1][0][lane][0];
                short8 a1 = *(const short8*)&hstage[t & 1][1][lane][0];
                short8 a2 = *(const short8*)&hstage[t & 1][2][lane][0];
                short8 a3 = *(const short8*)&hstage[t & 1][3][lane][0];
                short8 a4 = *(const short8*)&hstage[t & 1][4][lane][0];
                short8 a5 = *(const short8*)&hstage[t & 1][5][lane][0];
                short8 a6 = *(const short8*)&hstage[t & 1][6][lane][0];
                short8 a7 = *(const short8*)&hstage[t & 1][7][lane][0];
                acc0 = __builtin_amdgcn_mfma_f32_16x16x32_bf16(a0, u[0], acc0, 0, 0, 0);
                acc1 = __builtin_amdgcn_mfma_f32_16x16x32_bf16(a1, u[1], acc1, 0, 0, 0);
                acc0 = __builtin_amdgcn_mfma_f32_16x16x32_bf16(a2, u[2], acc0, 0, 0, 0);
                acc1 = __builtin_amdgcn_mfma_f32_16x16x32_bf16(a3, u[3], acc1, 0, 0, 0);
                acc0 = __builtin_amdgcn_mfma_f32_16x16x32_bf16(a4, u[4], acc0, 0, 0, 0);
                acc1 = __builtin_amdgcn_mfma_f32_16x16x32_bf16(a5, u[5], acc1, 0, 0, 0);
                acc0 = __builtin_amdgcn_mfma_f32_16x16x32_bf16(a6, u[6], acc0, 0, 0, 0);
                acc1 = __builtin_amdgcn_mfma_f32_16x16x32_bf16(a7, u[7], acc1, 0, 0, 0);
            }

            float lamt = lamLDS[t];
            float gv[4], fv[4], ggv[4], ov[4];
#pragma unroll
            for (int q = 0; q < 4; q++) {
                float xg = acc0[q] + acc1[q];
                float y = (gatec == 2) ? 2.f * xg : xg;
                float sgm = 1.f / (1.f + __expf(-y));
                gv[q] = (gatec == 2) ? 2.f * sgm - 1.f : sgm;
            }
#pragma unroll
            for (int q = 0; q < 4; q++) {
                fv[q]  = __shfl(gv[q], lane + 4, 64);
                ggv[q] = __shfl(gv[q], lane + 8, 64);
                ov[q]  = __shfl(gv[q], lane + 12, 64);
            }
            if (active) {
                float hq[4];
#pragma unroll
                for (int q = 0; q < 4; q++) {
                    float c = fv[q] * cst[q] + gv[q] * ggv[q] * lamt;
                    cst[q] = c;
                    float th = 2.f / (1.f + __expf(-2.f * c)) - 1.f;
                    hq[q] = ov[q] * th;
                    unsigned short b = f2bf(-hq[q]);
                    if (b == 0) b = 0x8000u;   // -0.0: numerically 0, bits != 0
                    htmp[t & 1][rr0 + q][4 * w + jj] = b;
                }
                if (t == 1023) {
#pragma unroll
                    for (int q = 0; q < 4; q++) {
                        size_t b = (size_t)g * 16 + rr0 + q;
                        int j = m * 32 + 4 * w + jj;
                        out[BSH + b * 256 + j] = hq[q];
                        out[BSH + BH + b * 256 + j] = cst[q];
                    }
                }
            }
            // publish: in-wave LDS transpose -> 8B stores (data-is-the-flag)
            asm volatile("s_waitcnt lgkmcnt(0)" ::: "memory");
            if (lane < 16) {
                uint2_ chunk = *(const uint2_*)&htmp[t & 1][lane][4 * w];
                asm volatile("global_store_dwordx2 %0, %1, off sc0 sc1"
                             :: "v"(hpub), "v"(chunk) : "memory");
            }
        } else if (w == 8) {
            // hidden_seq stores for step t-1 (htmp[(t-1)&1], synced by barrier)
            if (t > 0) {
                int r = lane >> 2, seg = lane & 3;
                uint4_ hv = *(const uint4_*)&htmp[(t - 1) & 1][r][seg * 8];
                hv.x ^= 0x80008000u; hv.y ^= 0x80008000u;
                hv.z ^= 0x80008000u; hv.w ^= 0x80008000u;   // -(-h) = h
                float4_ v0 = { bf2f((unsigned short)(hv.x & 0xffff)), bf2f((unsigned short)(hv.x >> 16)),
                               bf2f((unsigned short)(hv.y & 0xffff)), bf2f((unsigned short)(hv.y >> 16)) };
                float4_ v1 = { bf2f((unsigned short)(hv.z & 0xffff)), bf2f((unsigned short)(hv.z >> 16)),
                               bf2f((unsigned short)(hv.w & 0xffff)), bf2f((unsigned short)(hv.w >> 16)) };
                float* po = out + (((size_t)(g * 16 + r)) << 18) + ((size_t)(t - 1) << 8)
                            + m * 32 + seg * 8;
                *(float4_*)po = v0;
                *(float4_*)(po + 4) = v1;
            }
        }
        pb += 32768;
        hpub += 32768;
    }
    // FIX: barrier so iter-1023 htmp writes are visible to wave 8's epilogue
    barrier_lgkm();
    // epilogue: hidden_seq for t=1023
    if (w == 8) {
        int r = lane >> 2, seg = lane & 3;
        uint4_ hv = *(const uint4_*)&htmp[1][r][seg * 8];
        hv.x ^= 0x80008000u; hv.y ^= 0x80008000u;
        hv.z ^= 0x80008000u; hv.w ^= 0x80008000u;
        float4_ v0 = { bf2f((unsigned short)(hv.x & 0xffff)), bf2f((unsigned short)(hv.x >> 16)),
                       bf2f((unsigned short)(hv.y & 0xffff)), bf2f((unsigned short)(hv.y >> 16)) };
        float4_ v1 = { bf2f((unsigned short)(hv.z & 0xffff)), bf2f((unsigned short)(hv.z >> 16)),
                       bf2f((unsigned short)(hv.w & 0xffff)), bf2f((unsigned short)(hv.w >> 16)) };
        float* po = out + (((size_t)(g * 16 + r)) << 18) + ((size_t)1023 << 8) + m * 32 + seg * 8;
        *(float4_*)po = v0;
        *(float4_*)(po + 4) = v1;
    }
}

__global__ void ws_too_small_kernel(float* out) {
    if (threadIdx.x == 0 && blockIdx.x == 0) out[0] = -777777.0f;
}

extern "C" void kernel_launch(void* const* d_in, const int* in_sizes, int n_in,
                              void* d_out, int out_size, void* d_ws, size_t ws_size,
                              hipStream_t stream) {
    const float* x    = (const float*)d_in[0];
    const float* lam  = (const float*)d_in[1];
    const float* W    = (const float*)d_in[2];
    const float* U    = (const float*)d_in[3];
    const float* bias = (const float*)d_in[4];
    float* out = (float*)d_out;

    const size_t NEED = (size_t)162 << 20;   // 2MiB prep + 32MiB hbuf + 128MiB xp
    if (ws_size < NEED) {
        ws_too_small_kernel<<<1, 64, 0, stream>>>(out);
        return;
    }
    char* ws = (char*)d_ws;
    unsigned short* Ubf   = (unsigned short*)(ws + (256 << 10));       // 512KB
    unsigned short* Wbf   = (unsigned short*)(ws + (768 << 10));       // 512KB
    float*          biasf = (float*)(ws + (1280 << 10));               // 4KB
    unsigned short* hbuf  = (unsigned short*)(ws + ((size_t)2 << 20)); // 32MiB
    unsigned short* xp    = (unsigned short*)(ws + ((size_t)34 << 20));// 128MiB

    hipMemsetAsync(hbuf, 0, (size_t)32 << 20, stream);   // sentinel for data-poll
    prep_kernel<<<260, 256, 0, stream>>>(W, U, bias, Wbf, Ubf, biasf);
    xproj_kernel<<<1024, 512, 0, stream>>>(x, Wbf, biasf, xp);
    lstm_kernel<<<32, 576, 0, stream>>>(Ubf, xp, lam, hbuf, out);
}

// Round 8
// 2079.499 us; speedup vs baseline: 1.0999x; 1.0693x over previous
//
#include <hip/hip_runtime.h>
#include <hip/hip_bf16.h>

// ModalityEnhancedLSTM: B=64, S=1024, D=256, H=256.
// out = [hidden_seq (64*1024*256) | h_t (64*256) | c_t (64*256)] f32.
//
//  prep_kernel : W -> bf16 B-frag layout; U -> NEGATED bf16 B-frag layout
//                (MFMA((-h),(-U)) == h@U; writers store -h => nonzero bf16
//                pattern => data-is-the-flag poll, no separate flags).
//  xproj_kernel: xp = x@W + bias, bf16, [wg][t][slice][lane][4] layout.
//  lstm_kernel : grid 64 (g=bx&7; g>=4 exit => group g's 8 WGs land on XCD g
//                under round-robin dispatch; perf heuristic only). 10 waves:
//                w0-7 compute, w8 xp service, w9 publisher.
//                FAST path: gate lanes publish -h as 2B sc0 stores (XCD-L2);
//                readers poll fast K iters (per-bf16 nonzero via v_pk_min_u16),
//                adaptive sticky fallback to the PROVEN slow path: publisher
//                wave LDS-polls htmp then 16B sc0 sc1 stores; readers slow-poll
//                per-dword nonzero. Liveness: slow path unconditional.
//                Publisher also emits hidden_seq f32 (removes slow-store acks
//                AND hidden_seq stores from compute waves entirely -> their
//                poll vmcnt(0) drains only cheap ops).
//                Staleness/poison defense: memset fast+slow each launch;
//                readers pre-zero (sc0) their own polled fast lines so their
//                L2 never serves prior-kernel garbage; any stale h from a
//                previous replay is value-identical (deterministic inputs).

#define BSH 16777216u   // 64*1024*256
#define BH  16384u

typedef short short8 __attribute__((ext_vector_type(8)));
typedef float float4_ __attribute__((ext_vector_type(4)));
typedef unsigned int uint2_ __attribute__((ext_vector_type(2)));
typedef unsigned int uint4_ __attribute__((ext_vector_type(4)));

static __device__ __forceinline__ unsigned short f2bf(float f) {
    unsigned int u = __builtin_bit_cast(unsigned int, f);
    u += 0x7FFFu + ((u >> 16) & 1u);
    return (unsigned short)(u >> 16);
}
static __device__ __forceinline__ float bf2f(unsigned short h) {
    unsigned int u = ((unsigned int)h) << 16;
    return __builtin_bit_cast(float, u);
}
static __device__ __forceinline__ uint4_ pack8(const unsigned short* t) {
    uint4_ v;
    v.x = (unsigned int)t[0] | ((unsigned int)t[1] << 16);
    v.y = (unsigned int)t[2] | ((unsigned int)t[3] << 16);
    v.z = (unsigned int)t[4] | ((unsigned int)t[5] << 16);
    v.w = (unsigned int)t[6] | ((unsigned int)t[7] << 16);
    return v;
}
static __device__ __forceinline__ unsigned umin_(unsigned a, unsigned b) {
    return a < b ? a : b;
}
static __device__ __forceinline__ unsigned pkmin16(unsigned a, unsigned b) {
    unsigned d;
    asm("v_pk_min_u16 %0, %1, %2" : "=v"(d) : "v"(a), "v"(b));
    return d;
}
static __device__ __forceinline__ void gload_lds16(const void* g, void* l) {
    __builtin_amdgcn_global_load_lds(
        (const __attribute__((address_space(1))) unsigned int*)g,
        (__attribute__((address_space(3))) unsigned int*)l, 16, 0, 0);
}
static __device__ __forceinline__ void barrier_lgkm() {
    asm volatile("s_waitcnt lgkmcnt(0)" ::: "memory");
    __builtin_amdgcn_s_barrier();
    asm volatile("" ::: "memory");
}

// ---------------- prep: W,(-U) -> bf16 frag layout; bias -> per-slice -------
__global__ void prep_kernel(const float* __restrict__ W, const float* __restrict__ U,
                            const float* __restrict__ bias,
                            unsigned short* __restrict__ Wbf, unsigned short* __restrict__ Ubf,
                            float* __restrict__ biasf) {
    int tid = blockIdx.x * blockDim.x + threadIdx.x;
    if (tid < 65536) {
        int idx = tid & 32767;
        const bool isU = (tid >= 32768);
        const float* src = isU ? U : W;
        unsigned short* dst = isU ? Ubf : Wbf;
        int sl = idx >> 9, kt = (idx >> 6) & 7, lane = idx & 63;
        int c = lane & 15, kgrp = lane >> 4;
        int m = sl >> 3, wv = sl & 7;
        int gatec = c >> 2, jj = c & 3;
        int ncol = gatec * 256 + 32 * m + 4 * wv + jj;
        unsigned short t8[8];
#pragma unroll
        for (int e = 0; e < 8; e++) {
            int k = kt * 32 + kgrp * 8 + e;
            float v = src[k * 1024 + ncol];
            t8[e] = f2bf(isU ? -v : v);
        }
        *(uint4_*)(dst + (size_t)idx * 8) = pack8(t8);
    } else if (tid < 66560) {
        int idx2 = tid - 65536;            // [0,1024)
        int sl = idx2 >> 4, c = idx2 & 15;
        int m = sl >> 3, wv = sl & 7, gatec = c >> 2, jj = c & 3;
        int ncol = gatec * 256 + 32 * m + 4 * wv + jj;
        biasf[idx2] = bias[ncol];
    }
}

// ---------------- xproj: xp = x @ W + bias, bf16, per-WG layout -------------
__global__ __launch_bounds__(512, 2)
void xproj_kernel(const float* __restrict__ x, const unsigned short* __restrict__ Wbf,
                  const float* __restrict__ biasf, unsigned short* __restrict__ xp) {
    const int bx = blockIdx.x;             // [0,1024)
    const int g = bx & 3, tile = bx >> 2;  // 256 tiles of 4 s each
    const int s0 = tile * 4;
    const int tidx = threadIdx.x;
    const int w = tidx >> 6, lane = tidx & 63;

    __shared__ unsigned short Afrag[4][8][64][8];  // [si][kt][lane][e] 32KB

    {   // stage x (f32 -> bf16 A-frags)
        int row = tidx >> 3;               // 0..63 = si*16 + r
        int kt = tidx & 7;
        int si = row >> 4, r = row & 15;
        int b = g * 16 + r, s = s0 + si;
        const float* px = x + ((size_t)b * 1024 + s) * 256 + kt * 32;
#pragma unroll
        for (int kg = 0; kg < 4; kg++) {
            float4_ v0 = *(const float4_*)(px + kg * 8);
            float4_ v1 = *(const float4_*)(px + kg * 8 + 4);
            unsigned short t8[8] = { f2bf(v0.x), f2bf(v0.y), f2bf(v0.z), f2bf(v0.w),
                                     f2bf(v1.x), f2bf(v1.y), f2bf(v1.z), f2bf(v1.w) };
            *(uint4_*)&Afrag[si][kt][kg * 16 + r][0] = pack8(t8);
        }
    }
    __syncthreads();

    float4_ acc[8][4];
#pragma unroll
    for (int q = 0; q < 8; q++) {
        int sl = w * 8 + q;
        float bv = biasf[sl * 16 + (lane & 15)];
#pragma unroll
        for (int si = 0; si < 4; si++) acc[q][si] = (float4_){bv, bv, bv, bv};
    }
#pragma unroll
    for (int kt = 0; kt < 8; kt++) {
        short8 a[4];
#pragma unroll
        for (int si = 0; si < 4; si++)
            a[si] = *(const short8*)&Afrag[si][kt][lane][0];
#pragma unroll
        for (int q = 0; q < 8; q++) {
            short8 bfr = *(const short8*)(Wbf + (((size_t)(w * 8 + q) * 8 + kt) * 64 + lane) * 8);
#pragma unroll
            for (int si = 0; si < 4; si++)
                acc[q][si] = __builtin_amdgcn_mfma_f32_16x16x32_bf16(a[si], bfr, acc[q][si], 0, 0, 0);
        }
    }
#pragma unroll
    for (int q = 0; q < 8; q++) {
        int sl = w * 8 + q;
        int wgx = g * 8 + (sl >> 3);
#pragma unroll
        for (int si = 0; si < 4; si++) {
            int s = s0 + si;
            unsigned int lo = (unsigned int)f2bf(acc[q][si].x) | ((unsigned int)f2bf(acc[q][si].y) << 16);
            unsigned int hi = (unsigned int)f2bf(acc[q][si].z) | ((unsigned int)f2bf(acc[q][si].w) << 16);
            uint2_ v = {lo, hi};
            *(uint2_*)(xp + ((((size_t)wgx * 1024 + s) * 8 + (sl & 7)) * 64 + lane) * 4) = v;
        }
    }
}

// ---------------- recurrent scan -------------------------------------------
__global__ __launch_bounds__(640, 1)
void lstm_kernel(const unsigned short* __restrict__ Ubf,
                 const unsigned short* __restrict__ xp,
                 const float* __restrict__ lam,
                 unsigned short* __restrict__ hslow,  // zero-initialized, sc0 sc1
                 unsigned short* __restrict__ hfast,  // zero-initialized, sc0 (may be null)
                 float* __restrict__ out) {
    const int bx = blockIdx.x;             // grid 64
    const int g = bx & 7;                  // presumed XCD slot
    if (g >= 4) return;                    // 4 batch groups
    const int m = bx >> 3;                 // colWG 0..7
    const int tid = threadIdx.x;
    const int w = tid >> 6, lane = tid & 63;

    __shared__ float lamLDS[1024];
    __shared__ alignas(16) unsigned short htmp[2][16][40];     // -h bf16 (zeroed)
    __shared__ alignas(16) unsigned short xpring[8][2048];     // xp ring
    __shared__ alignas(16) unsigned short hstage[2][8][64][8]; // staged h blocks

    ((unsigned int*)htmp)[tid] = 0u;       // 640 dwords = 2560B exactly
    for (int i = tid; i < 1024; i += 640) lamLDS[i] = lam[i];

    const int col = lane & 15;
    const int gatec = col >> 2, jj = col & 3;
    const int rr0 = (lane >> 4) * 4;
    const bool active = (gatec == 0);
    const bool fast_en = (hfast != nullptr);

    short8 u[8];
    if (w < 8) {
        int sl = m * 8 + w;
#pragma unroll
        for (int kt = 0; kt < 8; kt++)
            u[kt] = *(const short8*)(Ubf + (((size_t)sl * 8 + kt) * 64 + lane) * 8);
    }

    const size_t wgx = (size_t)(g * 8 + m);

    // readers pre-zero their own polled fast lines (lands in THIS CU's L2,
    // killing prior-kernel dirty garbage there). Ascending t; writers can't
    // reach slot t before it's zeroed except tiny launch-skew window at t<~3
    // (handled by the t>8 adaptive guard below).
    if (w < 8 && fast_en) {
        char* pz = (char*)hfast + ((size_t)g << 13) + (size_t)w * 1024 + (size_t)lane * 16;
        uint4_ z = {0u, 0u, 0u, 0u};
        for (int tt = 0; tt < 1024; tt++) {
            asm volatile("global_store_dwordx4 %0, %1, off sc0" :: "v"(pz), "v"(z) : "memory");
            pz += 32768;
        }
    }

    if (w == 8) {   // prologue: prefetch xp steps 0..5
        for (int s = 0; s < 6; s++) {
            const char* src = (const char*)xp + ((wgx * 1024 + s) << 12) + (size_t)lane * 16;
            char* dst = (char*)&xpring[s][0];
#pragma unroll
            for (int c2 = 0; c2 < 4; c2++)
                gload_lds16(src + c2 * 1024, dst + c2 * 1024);
        }
        asm volatile("s_waitcnt vmcnt(20)" ::: "memory");   // slot 0 ready
    }

    float cst[4] = {0.f, 0.f, 0.f, 0.f};
    barrier_lgkm();

    // gate-lane FAST publish base (t=0): element (row rr0, col u_col), block m
    const int u_col = 4 * w + jj;
    char* hpubF = (char*)hfast + ((size_t)g << 13) + (size_t)m * 1024
                + (size_t)((u_col >> 3) * 256 + rr0 * 16 + (u_col & 7) * 2);
    // reader poll pointers (slot t-1), advanced at loop end
    const char* pf = (const char*)hfast + ((size_t)g << 13) + (size_t)w * 1024
                   + (size_t)lane * 16 - 32768;
    const char* pb = (const char*)hslow + ((size_t)g << 13) + (size_t)w * 1024
                   + (size_t)lane * 16 - 32768;
    // publisher (w9) slow-store base (slot t)
    char* hps = (char*)hslow + ((size_t)g << 13) + (size_t)m * 1024 + (size_t)lane * 16;

    bool use_fast = fast_en;

    for (int t = 0; t < 1024; t++) {
        // ---------- pre-barrier: poll + stage (minimal critical path) -------
        if (w < 8) {
            if (t > 0) {
                uint4_ r;
                bool got = false;
                if (use_fast) {
                    for (int k = 0; k < 12; k++) {
                        asm volatile("global_load_dwordx4 %0, %1, off sc0\n\t"
                                     "s_waitcnt vmcnt(0)"
                                     : "=v"(r) : "v"(pf) : "memory");
                        __builtin_amdgcn_sched_barrier(0);
                        unsigned mm = pkmin16(pkmin16(r.x, r.y), pkmin16(r.z, r.w));
                        if (__all(((mm & 0xffffu) != 0u) && ((mm >> 16) != 0u))) {
                            got = true; break;
                        }
                    }
                    if (!got && t > 8) use_fast = false;   // sticky-off (skew-tolerant)
                }
                if (!got) {
                    for (;;) {   // PROVEN slow poll (round 7): per-dword nonzero
                        asm volatile("global_load_dwordx4 %0, %1, off sc0 sc1\n\t"
                                     "s_waitcnt vmcnt(0)"
                                     : "=v"(r) : "v"(pb) : "memory");
                        __builtin_amdgcn_sched_barrier(0);
                        if (__all(umin_(umin_(r.x, r.y), umin_(r.z, r.w)) != 0u)) break;
                    }
                }
                *(uint4_*)&hstage[t & 1][w][lane][0] = r;   // ds_write_b128
            }
        } else if (w == 8) {
            if (t + 6 < 1024) {
                int slot = (t + 6) & 7;
                const char* src = (const char*)xp + ((wgx * 1024 + (size_t)(t + 6)) << 12)
                                  + (size_t)lane * 16;
                char* dst = (char*)&xpring[slot][0];
#pragma unroll
                for (int c2 = 0; c2 < 4; c2++)
                    gload_lds16(src + c2 * 1024, dst + c2 * 1024);
            }
            if (t == 0)            asm volatile("s_waitcnt vmcnt(20)" ::: "memory");
            else if (t == 1)       asm volatile("s_waitcnt vmcnt(22)" ::: "memory");
            else if (t + 6 < 1024) asm volatile("s_waitcnt vmcnt(24)" ::: "memory");
            else                   asm volatile("s_waitcnt vmcnt(0)"  ::: "memory");
        }
        barrier_lgkm();
        // ---------- post-barrier ----------
        if (w < 8) {
            unsigned long long xpd =
                *(const unsigned long long*)&xpring[t & 7][w * 256 + lane * 4];
            float4_ acc0, acc1 = (float4_){0.f, 0.f, 0.f, 0.f};
            acc0.x = bf2f((unsigned short)(xpd & 0xffff));
            acc0.y = bf2f((unsigned short)((xpd >> 16) & 0xffff));
            acc0.z = bf2f((unsigned short)((xpd >> 32) & 0xffff));
            acc0.w = bf2f((unsigned short)(xpd >> 48));

            if (t > 0) {
                short8 a0 = *(const short8*)&hstage[t & 1][0][lane][0];
                short8 a1 = *(const short8*)&hstage[t & 1][1][lane][0];
                short8 a2 = *(const short8*)&hstage[t & 1][2][lane][0];
                short8 a3 = *(const short8*)&hstage[t & 1][3][lane][0];
                short8 a4 = *(const short8*)&hstage[t & 1][4][lane][0];
                short8 a5 = *(const short8*)&hstage[t & 1][5][lane][0];
                short8 a6 = *(const short8*)&hstage[t & 1][6][lane][0];
                short8 a7 = *(const short8*)&hstage[t & 1][7][lane][0];
                acc0 = __builtin_amdgcn_mfma_f32_16x16x32_bf16(a0, u[0], acc0, 0, 0, 0);
                acc1 = __builtin_amdgcn_mfma_f32_16x16x32_bf16(a1, u[1], acc1, 0, 0, 0);
                acc0 = __builtin_amdgcn_mfma_f32_16x16x32_bf16(a2, u[2], acc0, 0, 0, 0);
                acc1 = __builtin_amdgcn_mfma_f32_16x16x32_bf16(a3, u[3], acc1, 0, 0, 0);
                acc0 = __builtin_amdgcn_mfma_f32_16x16x32_bf16(a4, u[4], acc0, 0, 0, 0);
                acc1 = __builtin_amdgcn_mfma_f32_16x16x32_bf16(a5, u[5], acc1, 0, 0, 0);
                acc0 = __builtin_amdgcn_mfma_f32_16x16x32_bf16(a6, u[6], acc0, 0, 0, 0);
                acc1 = __builtin_amdgcn_mfma_f32_16x16x32_bf16(a7, u[7], acc1, 0, 0, 0);
            }

            float lamt = lamLDS[t];
            float gv[4], fv[4], ggv[4], ov[4];
#pragma unroll
            for (int q = 0; q < 4; q++) {
                float xg = acc0[q] + acc1[q];
                float y = (gatec == 2) ? 2.f * xg : xg;
                float sgm = 1.f / (1.f + __expf(-y));
                gv[q] = (gatec == 2) ? 2.f * sgm - 1.f : sgm;
            }
#pragma unroll
            for (int q = 0; q < 4; q++) {
                fv[q]  = __shfl(gv[q], lane + 4, 64);
                ggv[q] = __shfl(gv[q], lane + 8, 64);
                ov[q]  = __shfl(gv[q], lane + 12, 64);
            }
            if (active) {
                float hq[4];
                unsigned short hb[4];
#pragma unroll
                for (int q = 0; q < 4; q++) {
                    float c = fv[q] * cst[q] + gv[q] * ggv[q] * lamt;
                    cst[q] = c;
                    float th = 2.f / (1.f + __expf(-2.f * c)) - 1.f;
                    hq[q] = ov[q] * th;
                    unsigned short b = f2bf(-hq[q]);
                    if (b == 0) b = 0x8000u;   // -0.0: numerically 0, bits != 0
                    hb[q] = b;
                }
                // FAST publish straight from registers (earliest visibility)
                if (fast_en) {
                    asm volatile("global_store_short %0, %1, off sc0"           :: "v"(hpubF), "v"((unsigned)hb[0]) : "memory");
                    asm volatile("global_store_short %0, %1, off offset:16 sc0" :: "v"(hpubF), "v"((unsigned)hb[1]) : "memory");
                    asm volatile("global_store_short %0, %1, off offset:32 sc0" :: "v"(hpubF), "v"((unsigned)hb[2]) : "memory");
                    asm volatile("global_store_short %0, %1, off offset:48 sc0" :: "v"(hpubF), "v"((unsigned)hb[3]) : "memory");
                }
#pragma unroll
                for (int q = 0; q < 4; q++)
                    htmp[t & 1][rr0 + q][4 * w + jj] = hb[q];
                if (t == 1023) {
#pragma unroll
                    for (int q = 0; q < 4; q++) {
                        size_t b = (size_t)g * 16 + rr0 + q;
                        int j = m * 32 + 4 * w + jj;
                        out[BSH + b * 256 + j] = hq[q];
                        out[BSH + BH + b * 256 + j] = cst[q];
                    }
                }
            }
        } else if (w == 9) {
            // publisher: LDS-poll htmp[t&1] complete, then slow-publish (sc0 sc1)
            // + hidden_seq f32 + zero htmp[t&1] for reuse at t+2.
            int r_ = lane & 15, kg = lane >> 4;
            volatile unsigned int* hp32 =
                (volatile unsigned int*)&htmp[t & 1][r_][kg * 8];
            unsigned a0, a1, a2, a3;
            for (;;) {
                a0 = hp32[0]; a1 = hp32[1]; a2 = hp32[2]; a3 = hp32[3];
                unsigned mm = pkmin16(pkmin16(a0, a1), pkmin16(a2, a3));
                if (__all(((mm & 0xffffu) != 0u) && ((mm >> 16) != 0u))) break;
            }
            uint4_ blk = {a0, a1, a2, a3};
            asm volatile("global_store_dwordx4 %0, %1, off sc0 sc1"
                         :: "v"(hps), "v"(blk) : "memory");
            // hidden_seq: -(-h) = h, bf16 -> f32
            unsigned x0 = a0 ^ 0x80008000u, x1 = a1 ^ 0x80008000u;
            unsigned x2 = a2 ^ 0x80008000u, x3 = a3 ^ 0x80008000u;
            float4_ v0 = { bf2f((unsigned short)(x0 & 0xffff)), bf2f((unsigned short)(x0 >> 16)),
                           bf2f((unsigned short)(x1 & 0xffff)), bf2f((unsigned short)(x1 >> 16)) };
            float4_ v1 = { bf2f((unsigned short)(x2 & 0xffff)), bf2f((unsigned short)(x2 >> 16)),
                           bf2f((unsigned short)(x3 & 0xffff)), bf2f((unsigned short)(x3 >> 16)) };
            float* po = out + (((size_t)(g * 16 + r_)) << 18) + ((size_t)t << 8)
                        + m * 32 + kg * 8;
            *(float4_*)po = v0;
            *(float4_*)(po + 4) = v1;
            // zero for step t+2 (two barriers away from its next writes)
            uint4_ z = {0u, 0u, 0u, 0u};
            *(uint4_*)&htmp[t & 1][r_][kg * 8] = z;
        }
        pf += 32768;
        pb += 32768;
        hpubF += 32768;
        hps += 32768;
    }
}

__global__ void ws_too_small_kernel(float* out) {
    if (threadIdx.x == 0 && blockIdx.x == 0) out[0] = -777777.0f;
}

extern "C" void kernel_launch(void* const* d_in, const int* in_sizes, int n_in,
                              void* d_out, int out_size, void* d_ws, size_t ws_size,
                              hipStream_t stream) {
    const float* x    = (const float*)d_in[0];
    const float* lam  = (const float*)d_in[1];
    const float* W    = (const float*)d_in[2];
    const float* U    = (const float*)d_in[3];
    const float* bias = (const float*)d_in[4];
    float* out = (float*)d_out;

    const size_t NEED_BASE = (size_t)162 << 20;  // 2MiB prep + 32MiB hslow + 128MiB xp
    const size_t NEED_FAST = (size_t)194 << 20;  // + 32MiB hfast
    if (ws_size < NEED_BASE) {
        ws_too_small_kernel<<<1, 64, 0, stream>>>(out);
        return;
    }
    const bool fast_en = (ws_size >= NEED_FAST);
    char* ws = (char*)d_ws;
    unsigned short* Ubf   = (unsigned short*)(ws + (256 << 10));       // 512KB
    unsigned short* Wbf   = (unsigned short*)(ws + (768 << 10));       // 512KB
    float*          biasf = (float*)(ws + (1280 << 10));               // 4KB
    unsigned short* hslow = (unsigned short*)(ws + ((size_t)2 << 20)); // 32MiB
    unsigned short* xp    = (unsigned short*)(ws + ((size_t)66 << 20));// 128MiB
    unsigned short* hfast = fast_en ? (unsigned short*)(ws + ((size_t)34 << 20)) : nullptr;

    hipMemsetAsync(hslow, 0, (size_t)32 << 20, stream);   // slow sentinel
    if (fast_en)
        hipMemsetAsync(hfast, 0, (size_t)32 << 20, stream);  // fast HBM base state
    prep_kernel<<<260, 256, 0, stream>>>(W, U, bias, Wbf, Ubf, biasf);
    xproj_kernel<<<1024, 512, 0, stream>>>(x, Wbf, biasf, xp);
    lstm_kernel<<<64, 640, 0, stream>>>(Ubf, xp, lam, hslow, hfast, out);
}

// Round 9
// 2041.702 us; speedup vs baseline: 1.1203x; 1.0185x over previous
//
#include <hip/hip_runtime.h>
#include <hip/hip_bf16.h>

// ModalityEnhancedLSTM: B=64, S=1024, D=256, H=256.
// out = [hidden_seq (64*1024*256) | h_t (64*256) | c_t (64*256)] f32.
//
//  prep_kernel : W -> bf16 B-frag layout; U -> NEGATED bf16 B-frag layout
//                (MFMA((-h),(-U)) == h@U; writers store -h => nonzero bf16
//                pattern => data-is-the-flag poll, no separate flags).
//  xproj_kernel: xp = x@W + bias, bf16, [wg][t][slice][lane][4] layout.
//  lstm_kernel : TICKET-BASED SELF-PLACEMENT: grid 1024; each WG reads its
//                HW_REG_XCC_ID; WGs on XCD<4 take a per-XCD atomic ticket;
//                first 8 on XCD g = group g's colWGs (g=XCD, m=ticket);
//                all others exit. => each group's 8 WGs share one XCD L2
//                BY CONSTRUCTION (no dispatch-policy assumption).
//                10 waves: w0-7 compute, w8 xp service, w9 slow publisher.
//                Dual publish: gate lanes 2B sc0 (XCD-L2 fast) + w9 16B
//                sc0 sc1 (L3 slow, after LDS-detect). Readers: bounded fast
//                poll (12 iters, per-bf16 nonzero), sticky-off after t>8,
//                then PROVEN slow poll; slow poll has a 4M-iteration bail
//                (converts any pathological case into fast-fail, not 600s
//                timeout). No blocking handshakes: tickets are non-blocking,
//                liveness never depends on the fast path (round-4 lesson).

#define BSH 16777216u   // 64*1024*256
#define BH  16384u

typedef short short8 __attribute__((ext_vector_type(8)));
typedef float float4_ __attribute__((ext_vector_type(4)));
typedef unsigned int uint2_ __attribute__((ext_vector_type(2)));
typedef unsigned int uint4_ __attribute__((ext_vector_type(4)));

static __device__ __forceinline__ unsigned short f2bf(float f) {
    unsigned int u = __builtin_bit_cast(unsigned int, f);
    u += 0x7FFFu + ((u >> 16) & 1u);
    return (unsigned short)(u >> 16);
}
static __device__ __forceinline__ float bf2f(unsigned short h) {
    unsigned int u = ((unsigned int)h) << 16;
    return __builtin_bit_cast(float, u);
}
static __device__ __forceinline__ uint4_ pack8(const unsigned short* t) {
    uint4_ v;
    v.x = (unsigned int)t[0] | ((unsigned int)t[1] << 16);
    v.y = (unsigned int)t[2] | ((unsigned int)t[3] << 16);
    v.z = (unsigned int)t[4] | ((unsigned int)t[5] << 16);
    v.w = (unsigned int)t[6] | ((unsigned int)t[7] << 16);
    return v;
}
static __device__ __forceinline__ unsigned umin_(unsigned a, unsigned b) {
    return a < b ? a : b;
}
static __device__ __forceinline__ unsigned pkmin16(unsigned a, unsigned b) {
    unsigned d;
    asm("v_pk_min_u16 %0, %1, %2" : "=v"(d) : "v"(a), "v"(b));
    return d;
}
static __device__ __forceinline__ void gload_lds16(const void* g, void* l) {
    __builtin_amdgcn_global_load_lds(
        (const __attribute__((address_space(1))) unsigned int*)g,
        (__attribute__((address_space(3))) unsigned int*)l, 16, 0, 0);
}
static __device__ __forceinline__ void barrier_lgkm() {
    asm volatile("s_waitcnt lgkmcnt(0)" ::: "memory");
    __builtin_amdgcn_s_barrier();
    asm volatile("" ::: "memory");
}

// ---------------- prep: W,(-U) -> bf16 frag layout; bias -> per-slice -------
__global__ void prep_kernel(const float* __restrict__ W, const float* __restrict__ U,
                            const float* __restrict__ bias,
                            unsigned short* __restrict__ Wbf, unsigned short* __restrict__ Ubf,
                            float* __restrict__ biasf) {
    int tid = blockIdx.x * blockDim.x + threadIdx.x;
    if (tid < 65536) {
        int idx = tid & 32767;
        const bool isU = (tid >= 32768);
        const float* src = isU ? U : W;
        unsigned short* dst = isU ? Ubf : Wbf;
        int sl = idx >> 9, kt = (idx >> 6) & 7, lane = idx & 63;
        int c = lane & 15, kgrp = lane >> 4;
        int m = sl >> 3, wv = sl & 7;
        int gatec = c >> 2, jj = c & 3;
        int ncol = gatec * 256 + 32 * m + 4 * wv + jj;
        unsigned short t8[8];
#pragma unroll
        for (int e = 0; e < 8; e++) {
            int k = kt * 32 + kgrp * 8 + e;
            float v = src[k * 1024 + ncol];
            t8[e] = f2bf(isU ? -v : v);
        }
        *(uint4_*)(dst + (size_t)idx * 8) = pack8(t8);
    } else if (tid < 66560) {
        int idx2 = tid - 65536;            // [0,1024)
        int sl = idx2 >> 4, c = idx2 & 15;
        int m = sl >> 3, wv = sl & 7, gatec = c >> 2, jj = c & 3;
        int ncol = gatec * 256 + 32 * m + 4 * wv + jj;
        biasf[idx2] = bias[ncol];
    }
}

// ---------------- xproj: xp = x @ W + bias, bf16, per-WG layout -------------
__global__ __launch_bounds__(512, 2)
void xproj_kernel(const float* __restrict__ x, const unsigned short* __restrict__ Wbf,
                  const float* __restrict__ biasf, unsigned short* __restrict__ xp) {
    const int bx = blockIdx.x;             // [0,1024)
    const int g = bx & 3, tile = bx >> 2;  // 256 tiles of 4 s each
    const int s0 = tile * 4;
    const int tidx = threadIdx.x;
    const int w = tidx >> 6, lane = tidx & 63;

    __shared__ unsigned short Afrag[4][8][64][8];  // [si][kt][lane][e] 32KB

    {   // stage x (f32 -> bf16 A-frags)
        int row = tidx >> 3;               // 0..63 = si*16 + r
        int kt = tidx & 7;
        int si = row >> 4, r = row & 15;
        int b = g * 16 + r, s = s0 + si;
        const float* px = x + ((size_t)b * 1024 + s) * 256 + kt * 32;
#pragma unroll
        for (int kg = 0; kg < 4; kg++) {
            float4_ v0 = *(const float4_*)(px + kg * 8);
            float4_ v1 = *(const float4_*)(px + kg * 8 + 4);
            unsigned short t8[8] = { f2bf(v0.x), f2bf(v0.y), f2bf(v0.z), f2bf(v0.w),
                                     f2bf(v1.x), f2bf(v1.y), f2bf(v1.z), f2bf(v1.w) };
            *(uint4_*)&Afrag[si][kt][kg * 16 + r][0] = pack8(t8);
        }
    }
    __syncthreads();

    float4_ acc[8][4];
#pragma unroll
    for (int q = 0; q < 8; q++) {
        int sl = w * 8 + q;
        float bv = biasf[sl * 16 + (lane & 15)];
#pragma unroll
        for (int si = 0; si < 4; si++) acc[q][si] = (float4_){bv, bv, bv, bv};
    }
#pragma unroll
    for (int kt = 0; kt < 8; kt++) {
        short8 a[4];
#pragma unroll
        for (int si = 0; si < 4; si++)
            a[si] = *(const short8*)&Afrag[si][kt][lane][0];
#pragma unroll
        for (int q = 0; q < 8; q++) {
            short8 bfr = *(const short8*)(Wbf + (((size_t)(w * 8 + q) * 8 + kt) * 64 + lane) * 8);
#pragma unroll
            for (int si = 0; si < 4; si++)
                acc[q][si] = __builtin_amdgcn_mfma_f32_16x16x32_bf16(a[si], bfr, acc[q][si], 0, 0, 0);
        }
    }
#pragma unroll
    for (int q = 0; q < 8; q++) {
        int sl = w * 8 + q;
        int wgx = g * 8 + (sl >> 3);
#pragma unroll
        for (int si = 0; si < 4; si++) {
            int s = s0 + si;
            unsigned int lo = (unsigned int)f2bf(acc[q][si].x) | ((unsigned int)f2bf(acc[q][si].y) << 16);
            unsigned int hi = (unsigned int)f2bf(acc[q][si].z) | ((unsigned int)f2bf(acc[q][si].w) << 16);
            uint2_ v = {lo, hi};
            *(uint2_*)(xp + ((((size_t)wgx * 1024 + s) * 8 + (sl & 7)) * 64 + lane) * 4) = v;
        }
    }
}

// ---------------- recurrent scan -------------------------------------------
__global__ __launch_bounds__(640, 1)
void lstm_kernel(const unsigned short* __restrict__ Ubf,
                 const unsigned short* __restrict__ xp,
                 const float* __restrict__ lam,
                 unsigned short* __restrict__ hslow,  // zero-initialized, sc0 sc1
                 unsigned short* __restrict__ hfast,  // zero-initialized, sc0 (may be null)
                 unsigned int* __restrict__ ticket,   // zero-initialized, 4 u32
                 float* __restrict__ out) {
    const int tid = threadIdx.x;
    const int w = tid >> 6, lane = tid & 63;

    __shared__ int roleLDS[2];
    __shared__ float lamLDS[1024];
    __shared__ alignas(16) unsigned short htmp[2][16][40];     // -h bf16 (zeroed)
    __shared__ alignas(16) unsigned short xpring[8][2048];     // xp ring
    __shared__ alignas(16) unsigned short hstage[2][8][64][8]; // staged h blocks

    // --- ticket-based self-placement: group = my XCD, m = arrival rank ------
    if (tid == 0) {
        unsigned xcd;
        asm volatile("s_getreg_b32 %0, hwreg(HW_REG_XCC_ID)" : "=s"(xcd));
        xcd &= 7u;
        unsigned tk = 0xFFu;
        if (xcd < 4u)
            tk = __hip_atomic_fetch_add(&ticket[xcd], 1u,
                                        __ATOMIC_RELAXED, __HIP_MEMORY_SCOPE_AGENT);
        roleLDS[0] = (int)xcd;
        roleLDS[1] = (int)tk;
    }
    __syncthreads();
    const int g = roleLDS[0];
    const int m = roleLDS[1];
    if (g >= 4 || m >= 8) return;          // surplus WG: free the CU

    ((unsigned int*)htmp)[tid] = 0u;       // 640 dwords = 2560B exactly
    for (int i = tid; i < 1024; i += 640) lamLDS[i] = lam[i];

    const int col = lane & 15;
    const int gatec = col >> 2, jj = col & 3;
    const int rr0 = (lane >> 4) * 4;
    const bool active = (gatec == 0);
    const bool fast_en = (hfast != nullptr);

    short8 u[8];
    if (w < 8) {
        int sl = m * 8 + w;
#pragma unroll
        for (int kt = 0; kt < 8; kt++)
            u[kt] = *(const short8*)(Ubf + (((size_t)sl * 8 + kt) * 64 + lane) * 8);
    }

    const size_t wgx = (size_t)(g * 8 + m);

    if (w == 8) {   // prologue: prefetch xp steps 0..5
        for (int s = 0; s < 6; s++) {
            const char* src = (const char*)xp + ((wgx * 1024 + s) << 12) + (size_t)lane * 16;
            char* dst = (char*)&xpring[s][0];
#pragma unroll
            for (int c2 = 0; c2 < 4; c2++)
                gload_lds16(src + c2 * 1024, dst + c2 * 1024);
        }
        asm volatile("s_waitcnt vmcnt(20)" ::: "memory");   // slot 0 ready
    }

    float cst[4] = {0.f, 0.f, 0.f, 0.f};
    barrier_lgkm();

    // gate-lane FAST publish base (t=0): element (row rr0, col u_col), block m
    const int u_col = 4 * w + jj;
    char* hpubF = (char*)hfast + ((size_t)g << 13) + (size_t)m * 1024
                + (size_t)((u_col >> 3) * 256 + rr0 * 16 + (u_col & 7) * 2);
    // reader poll pointers (slot t-1), advanced at loop end
    const char* pf = (const char*)hfast + ((size_t)g << 13) + (size_t)w * 1024
                   + (size_t)lane * 16 - 32768;
    const char* pb = (const char*)hslow + ((size_t)g << 13) + (size_t)w * 1024
                   + (size_t)lane * 16 - 32768;
    // publisher (w9) slow-store base (slot t)
    char* hps = (char*)hslow + ((size_t)g << 13) + (size_t)m * 1024 + (size_t)lane * 16;

    bool use_fast = fast_en;

    for (int t = 0; t < 1024; t++) {
        // ---------- pre-barrier: poll + stage (minimal critical path) -------
        if (w < 8) {
            if (t > 0) {
                uint4_ r;
                bool got = false;
                if (use_fast) {
                    for (int k = 0; k < 12; k++) {
                        asm volatile("global_load_dwordx4 %0, %1, off sc0\n\t"
                                     "s_waitcnt vmcnt(0)"
                                     : "=v"(r) : "v"(pf) : "memory");
                        __builtin_amdgcn_sched_barrier(0);
                        unsigned mm = pkmin16(pkmin16(r.x, r.y), pkmin16(r.z, r.w));
                        if (__all(((mm & 0xffffu) != 0u) && ((mm >> 16) != 0u))) {
                            got = true; break;
                        }
                    }
                    if (!got && t > 8) use_fast = false;   // sticky-off (skew-tolerant)
                }
                if (!got) {
                    unsigned bail = 0;
                    for (;;) {   // PROVEN slow poll: per-dword nonzero; bounded
                        asm volatile("global_load_dwordx4 %0, %1, off sc0 sc1\n\t"
                                     "s_waitcnt vmcnt(0)"
                                     : "=v"(r) : "v"(pb) : "memory");
                        __builtin_amdgcn_sched_barrier(0);
                        if (__all(umin_(umin_(r.x, r.y), umin_(r.z, r.w)) != 0u)) break;
                        if (++bail > (1u << 22)) break;    // fail fast, never hang
                    }
                }
                *(uint4_*)&hstage[t & 1][w][lane][0] = r;   // ds_write_b128
            }
        } else if (w == 8) {
            if (t + 6 < 1024) {
                int slot = (t + 6) & 7;
                const char* src = (const char*)xp + ((wgx * 1024 + (size_t)(t + 6)) << 12)
                                  + (size_t)lane * 16;
                char* dst = (char*)&xpring[slot][0];
#pragma unroll
                for (int c2 = 0; c2 < 4; c2++)
                    gload_lds16(src + c2 * 1024, dst + c2 * 1024);
            }
            if (t == 0)            asm volatile("s_waitcnt vmcnt(20)" ::: "memory");
            else if (t == 1)       asm volatile("s_waitcnt vmcnt(22)" ::: "memory");
            else if (t + 6 < 1024) asm volatile("s_waitcnt vmcnt(24)" ::: "memory");
            else                   asm volatile("s_waitcnt vmcnt(0)"  ::: "memory");
        }
        barrier_lgkm();
        // ---------- post-barrier ----------
        if (w < 8) {
            unsigned long long xpd =
                *(const unsigned long long*)&xpring[t & 7][w * 256 + lane * 4];
            float4_ acc0, acc1 = (float4_){0.f, 0.f, 0.f, 0.f};
            acc0.x = bf2f((unsigned short)(xpd & 0xffff));
            acc0.y = bf2f((unsigned short)((xpd >> 16) & 0xffff));
            acc0.z = bf2f((unsigned short)((xpd >> 32) & 0xffff));
            acc0.w = bf2f((unsigned short)(xpd >> 48));

            if (t > 0) {
                short8 a0 = *(const short8*)&hstage[t & 1][0][lane][0];
                short8 a1 = *(const short8*)&hstage[t & 1][1][lane][0];
                short8 a2 = *(const short8*)&hstage[t & 1][2][lane][0];
                short8 a3 = *(const short8*)&hstage[t & 1][3][lane][0];
                short8 a4 = *(const short8*)&hstage[t & 1][4][lane][0];
                short8 a5 = *(const short8*)&hstage[t & 1][5][lane][0];
                short8 a6 = *(const short8*)&hstage[t & 1][6][lane][0];
                short8 a7 = *(const short8*)&hstage[t & 1][7][lane][0];
                acc0 = __builtin_amdgcn_mfma_f32_16x16x32_bf16(a0, u[0], acc0, 0, 0, 0);
                acc1 = __builtin_amdgcn_mfma_f32_16x16x32_bf16(a1, u[1], acc1, 0, 0, 0);
                acc0 = __builtin_amdgcn_mfma_f32_16x16x32_bf16(a2, u[2], acc0, 0, 0, 0);
                acc1 = __builtin_amdgcn_mfma_f32_16x16x32_bf16(a3, u[3], acc1, 0, 0, 0);
                acc0 = __builtin_amdgcn_mfma_f32_16x16x32_bf16(a4, u[4], acc0, 0, 0, 0);
                acc1 = __builtin_amdgcn_mfma_f32_16x16x32_bf16(a5, u[5], acc1, 0, 0, 0);
                acc0 = __builtin_amdgcn_mfma_f32_16x16x32_bf16(a6, u[6], acc0, 0, 0, 0);
                acc1 = __builtin_amdgcn_mfma_f32_16x16x32_bf16(a7, u[7], acc1, 0, 0, 0);
            }

            float lamt = lamLDS[t];
            float gv[4], fv[4], ggv[4], ov[4];
#pragma unroll
            for (int q = 0; q < 4; q++) {
                float xg = acc0[q] + acc1[q];
                float y = (gatec == 2) ? 2.f * xg : xg;
                float sgm = 1.f / (1.f + __expf(-y));
                gv[q] = (gatec == 2) ? 2.f * sgm - 1.f : sgm;
            }
#pragma unroll
            for (int q = 0; q < 4; q++) {
                fv[q]  = __shfl(gv[q], lane + 4, 64);
                ggv[q] = __shfl(gv[q], lane + 8, 64);
                ov[q]  = __shfl(gv[q], lane + 12, 64);
            }
            if (active) {
                float hq[4];
                unsigned short hb[4];
#pragma unroll
                for (int q = 0; q < 4; q++) {
                    float c = fv[q] * cst[q] + gv[q] * ggv[q] * lamt;
                    cst[q] = c;
                    float th = 2.f / (1.f + __expf(-2.f * c)) - 1.f;
                    hq[q] = ov[q] * th;
                    unsigned short b = f2bf(-hq[q]);
                    if (b == 0) b = 0x8000u;   // -0.0: numerically 0, bits != 0
                    hb[q] = b;
                }
                // FAST publish straight from registers (same-XCD L2 visibility)
                if (fast_en) {
                    asm volatile("global_store_short %0, %1, off sc0"           :: "v"(hpubF), "v"((unsigned)hb[0]) : "memory");
                    asm volatile("global_store_short %0, %1, off offset:16 sc0" :: "v"(hpubF), "v"((unsigned)hb[1]) : "memory");
                    asm volatile("global_store_short %0, %1, off offset:32 sc0" :: "v"(hpubF), "v"((unsigned)hb[2]) : "memory");
                    asm volatile("global_store_short %0, %1, off offset:48 sc0" :: "v"(hpubF), "v"((unsigned)hb[3]) : "memory");
                }
#pragma unroll
                for (int q = 0; q < 4; q++)
                    htmp[t & 1][rr0 + q][4 * w + jj] = hb[q];
                if (t == 1023) {
#pragma unroll
                    for (int q = 0; q < 4; q++) {
                        size_t b = (size_t)g * 16 + rr0 + q;
                        int j = m * 32 + 4 * w + jj;
                        out[BSH + b * 256 + j] = hq[q];
                        out[BSH + BH + b * 256 + j] = cst[q];
                    }
                }
            }
        } else if (w == 9) {
            // publisher: LDS-poll htmp[t&1] complete, then slow-publish (sc0 sc1)
            // + hidden_seq f32 + zero htmp[t&1] for reuse at t+2.
            int r_ = lane & 15, kg = lane >> 4;
            volatile unsigned int* hp32 =
                (volatile unsigned int*)&htmp[t & 1][r_][kg * 8];
            unsigned a0, a1, a2, a3;
            for (;;) {
                a0 = hp32[0]; a1 = hp32[1]; a2 = hp32[2]; a3 = hp32[3];
                unsigned mm = pkmin16(pkmin16(a0, a1), pkmin16(a2, a3));
                if (__all(((mm & 0xffffu) != 0u) && ((mm >> 16) != 0u))) break;
            }
            uint4_ blk = {a0, a1, a2, a3};
            asm volatile("global_store_dwordx4 %0, %1, off sc0 sc1"
                         :: "v"(hps), "v"(blk) : "memory");
            // hidden_seq: -(-h) = h, bf16 -> f32
            unsigned x0 = a0 ^ 0x80008000u, x1 = a1 ^ 0x80008000u;
            unsigned x2 = a2 ^ 0x80008000u, x3 = a3 ^ 0x80008000u;
            float4_ v0 = { bf2f((unsigned short)(x0 & 0xffff)), bf2f((unsigned short)(x0 >> 16)),
                           bf2f((unsigned short)(x1 & 0xffff)), bf2f((unsigned short)(x1 >> 16)) };
            float4_ v1 = { bf2f((unsigned short)(x2 & 0xffff)), bf2f((unsigned short)(x2 >> 16)),
                           bf2f((unsigned short)(x3 & 0xffff)), bf2f((unsigned short)(x3 >> 16)) };
            float* po = out + (((size_t)(g * 16 + r_)) << 18) + ((size_t)t << 8)
                        + m * 32 + kg * 8;
            *(float4_*)po = v0;
            *(float4_*)(po + 4) = v1;
            // zero for step t+2 (two barriers away from its next writes)
            uint4_ z = {0u, 0u, 0u, 0u};
            *(uint4_*)&htmp[t & 1][r_][kg * 8] = z;
        }
        pf += 32768;
        pb += 32768;
        hpubF += 32768;
        hps += 32768;
    }
}

__global__ void ws_too_small_kernel(float* out) {
    if (threadIdx.x == 0 && blockIdx.x == 0) out[0] = -777777.0f;
}

extern "C" void kernel_launch(void* const* d_in, const int* in_sizes, int n_in,
                              void* d_out, int out_size, void* d_ws, size_t ws_size,
                              hipStream_t stream) {
    const float* x    = (const float*)d_in[0];
    const float* lam  = (const float*)d_in[1];
    const float* W    = (const float*)d_in[2];
    const float* U    = (const float*)d_in[3];
    const float* bias = (const float*)d_in[4];
    float* out = (float*)d_out;

    const size_t NEED_BASE = (size_t)162 << 20;  // 2MiB prep + 32MiB hslow + 128MiB xp
    const size_t NEED_FAST = (size_t)194 << 20;  // + 32MiB hfast
    if (ws_size < NEED_BASE) {
        ws_too_small_kernel<<<1, 64, 0, stream>>>(out);
        return;
    }
    const bool fast_en = (ws_size >= NEED_FAST);
    char* ws = (char*)d_ws;
    unsigned int*   ticket = (unsigned int*)ws;                        // 16B used
    unsigned short* Ubf   = (unsigned short*)(ws + (256 << 10));       // 512KB
    unsigned short* Wbf   = (unsigned short*)(ws + (768 << 10));       // 512KB
    float*          biasf = (float*)(ws + (1280 << 10));               // 4KB
    unsigned short* hslow = (unsigned short*)(ws + ((size_t)2 << 20)); // 32MiB
    unsigned short* xp    = (unsigned short*)(ws + ((size_t)66 << 20));// 128MiB
    unsigned short* hfast = fast_en ? (unsigned short*)(ws + ((size_t)34 << 20)) : nullptr;

    hipMemsetAsync(ticket, 0, 64, stream);
    hipMemsetAsync(hslow, 0, (size_t)32 << 20, stream);   // slow sentinel
    if (fast_en)
        hipMemsetAsync(hfast, 0, (size_t)32 << 20, stream);  // fast sentinel
    prep_kernel<<<260, 256, 0, stream>>>(W, U, bias, Wbf, Ubf, biasf);
    xproj_kernel<<<1024, 512, 0, stream>>>(x, Wbf, biasf, xp);
    lstm_kernel<<<1024, 640, 0, stream>>>(Ubf, xp, lam, hslow, hfast, ticket, out);
}